// Round 9
// baseline (427.460 us; speedup 1.0000x reference)
//
#include <hip/hip_runtime.h>
#include <hip/hip_bf16.h>
#include <cmath>

typedef __attribute__((ext_vector_type(8))) short short8;
typedef __attribute__((ext_vector_type(4))) float f32x4;

#define MFMA16(a, b, c) __builtin_amdgcn_mfma_f32_16x16x32_bf16((a), (b), (c), 0, 0, 0)

static constexpr int BB = 16, NN = 2048, DD = 256, HH = 256;

__device__ inline unsigned short f2bf(float f) {
    union { float f; unsigned int u; } v; v.f = f;
    unsigned int r = v.u + 0x7fffu + ((v.u >> 16) & 1u);
    return (unsigned short)(r >> 16);
}
__device__ inline float bf2f(unsigned short u) {
    union { unsigned int u; float f; } v; v.u = ((unsigned int)u) << 16;
    return v.f;
}
__device__ inline float gelu_exact(float x) {
    return 0.5f * x * (1.0f + erff(x * 0.7071067811865475f));
}
__device__ inline void gload_lds16(const void* g, void* l) {
    __builtin_amdgcn_global_load_lds(
        (const __attribute__((address_space(1))) unsigned int*)g,
        (__attribute__((address_space(3))) unsigned int*)l, 16, 0, 0);
}
__device__ inline void fence_mem() { asm volatile("" ::: "memory"); }

// ---- tiled weight transpose: fp32 [256][N] -> bf16 [N][256], coalesced ----
__global__ __launch_bounds__(256) void transposeT_k(const float* __restrict__ W1b,
                                                    const float* __restrict__ Wqkv,
                                                    const float* __restrict__ W2a,
                                                    unsigned short* __restrict__ W1bT,
                                                    unsigned short* __restrict__ WqkvT,
                                                    unsigned short* __restrict__ W2aT) {
    __shared__ float tl[64][65];
    int bid = blockIdx.x;  // 80 blocks: 16 W1b, 48 Wqkv, 16 W2a
    const float* src;
    unsigned short* dst;
    int N, tn, tk;
    if (bid < 16) {
        src = W1b; dst = W1bT; N = 256; tn = bid & 3; tk = bid >> 2;
    } else if (bid < 64) {
        int t2 = bid - 16;
        src = Wqkv; dst = WqkvT; N = 768; tn = t2 % 12; tk = t2 / 12;
    } else {
        int t2 = bid - 64;
        src = W2a; dst = W2aT; N = 256; tn = t2 & 3; tk = t2 >> 2;
    }
    int n0 = tn * 64, k0 = tk * 64;
    int t = threadIdx.x;
#pragma unroll
    for (int j = 0; j < 4; j++) {
        int row = (t >> 4) * 4 + j;
        f32x4 v = *(const f32x4*)(src + (size_t)(k0 + row) * N + n0 + (t & 15) * 4);
#pragma unroll
        for (int e = 0; e < 4; e++) tl[row][(t & 15) * 4 + e] = v[e];
    }
    __syncthreads();
    int n = t >> 2, cb = (t & 3) * 16;
    short8 a, b;
#pragma unroll
    for (int e = 0; e < 8; e++) {
        a[e] = (short)f2bf(tl[cb + e][n]);
        b[e] = (short)f2bf(tl[cb + 8 + e][n]);
    }
    *(short8*)(dst + (size_t)(n0 + n) * 256 + k0 + cb) = a;
    *(short8*)(dst + (size_t)(n0 + n) * 256 + k0 + cb + 8) = b;
}

// ---- fused FFN1 + qkv: t inline -> h (per-wave LDS) -> q,k,v ----
__global__ __launch_bounds__(256) void ffn_qkv_k(const float* __restrict__ x,
                                                 const float* __restrict__ grd,
                                                 const float* __restrict__ W1a,
                                                 const float* __restrict__ b1a,
                                                 const unsigned short* __restrict__ W1bT,
                                                 const float* __restrict__ b1b,
                                                 const unsigned short* __restrict__ WqkvT,
                                                 unsigned short* __restrict__ qo,
                                                 unsigned short* __restrict__ ko,
                                                 unsigned short* __restrict__ vo) {
    __shared__ unsigned short h_lds[4][16 * 256];
    const int w = threadIdx.x >> 6, lane = threadIdx.x & 63;
    const int c = lane & 15, g = lane >> 4;
    const int rb = blockIdx.x * 64 + w * 16;
    const int bb = (blockIdx.x * 64) >> 11;
    const int rowinb = (rb & (NN - 1)) + c;

    const int p = rb + c;
    const float xv = x[p];
    const float gv = grd[p & (NN - 1)];
    short8 tf[8];
#pragma unroll
    for (int kc = 0; kc < 8; kc++) {
        int j0 = kc * 32 + g * 8;
#pragma unroll
        for (int e = 0; e < 8; e += 4) {
            f32x4 wa = *(const f32x4*)(W1a + j0 + e);
            f32x4 wb = *(const f32x4*)(W1a + 256 + j0 + e);
            f32x4 ba = *(const f32x4*)(b1a + j0 + e);
#pragma unroll
            for (int q = 0; q < 4; q++) {
                float v = xv * wa[q] + gv * wb[q] + ba[q];
                tf[kc][e + q] = (short)f2bf(gelu_exact(v));
            }
        }
    }

    f32x4 acc[16];
#pragma unroll
    for (int n = 0; n < 16; n++) acc[n] = (f32x4){0.f, 0.f, 0.f, 0.f};
#pragma unroll
    for (int kc = 0; kc < 8; kc++) {
        short8 a = tf[kc];
#pragma unroll
        for (int n = 0; n < 16; n++) {
            short8 bfr = *(const short8*)(W1bT + (size_t)(n * 16 + c) * 256 + kc * 32 + g * 8);
            acc[n] = MFMA16(a, bfr, acc[n]);
        }
    }
    unsigned short* hl = &h_lds[w][0];
#pragma unroll
    for (int n = 0; n < 16; n++) {
        int col = n * 16 + c;
        float bv = b1b[col];
#pragma unroll
        for (int r = 0; r < 4; r++) {
            int row = g * 4 + r;
            hl[row * 256 + (col ^ ((row & 7) << 3))] = f2bf(acc[n][r] + bv);
        }
    }
    short8 hf[8];
#pragma unroll
    for (int kc = 0; kc < 8; kc++) {
        hf[kc] = *(const short8*)(hl + c * 256 + ((kc * 32 + g * 8) ^ ((c & 7) << 3)));
    }

    // q (scaled 1/16)
#pragma unroll
    for (int n = 0; n < 16; n++) acc[n] = (f32x4){0.f, 0.f, 0.f, 0.f};
#pragma unroll
    for (int kc = 0; kc < 8; kc++) {
        short8 a = hf[kc];
#pragma unroll
        for (int n = 0; n < 16; n++) {
            short8 bfr = *(const short8*)(WqkvT + (size_t)(n * 16 + c) * 256 + kc * 32 + g * 8);
            acc[n] = MFMA16(a, bfr, acc[n]);
        }
    }
#pragma unroll
    for (int n = 0; n < 16; n++)
#pragma unroll
        for (int r = 0; r < 4; r++)
            qo[(size_t)(rb + g * 4 + r) * 256 + n * 16 + c] = f2bf(acc[n][r] * 0.0625f);

    // k
#pragma unroll
    for (int n = 0; n < 16; n++) acc[n] = (f32x4){0.f, 0.f, 0.f, 0.f};
#pragma unroll
    for (int kc = 0; kc < 8; kc++) {
        short8 a = hf[kc];
#pragma unroll
        for (int n = 0; n < 16; n++) {
            short8 bfr = *(const short8*)(WqkvT + (size_t)(256 + n * 16 + c) * 256 + kc * 32 + g * 8);
            acc[n] = MFMA16(a, bfr, acc[n]);
        }
    }
#pragma unroll
    for (int n = 0; n < 16; n++)
#pragma unroll
        for (int r = 0; r < 4; r++)
            ko[(size_t)(rb + g * 4 + r) * 256 + n * 16 + c] = f2bf(acc[n][r]);

    // v (swapped operands -> v^T)
#pragma unroll
    for (int m = 0; m < 16; m++) acc[m] = (f32x4){0.f, 0.f, 0.f, 0.f};
#pragma unroll
    for (int kc = 0; kc < 8; kc++) {
        short8 b = hf[kc];
#pragma unroll
        for (int m = 0; m < 16; m++) {
            short8 afr = *(const short8*)(WqkvT + (size_t)(512 + m * 16 + c) * 256 + kc * 32 + g * 8);
            acc[m] = MFMA16(afr, b, acc[m]);
        }
    }
#pragma unroll
    for (int m = 0; m < 16; m++) {
#pragma unroll
        for (int r = 0; r < 4; r++) {
            int dcol = m * 16 + g * 4 + r;
            vo[((size_t)(bb * 256 + dcol)) * NN + rowinb] = f2bf(acc[m][r]);
        }
    }
}

// ---- flash attention, split-K x2: 1024 blocks, 36KB single-buffer LDS, no VGPR cap ----
typedef struct { float m, l; } rowstat;

__global__ __launch_bounds__(256) void attn_k(const unsigned short* __restrict__ qb,
                                              const unsigned short* __restrict__ kb,
                                              const unsigned short* __restrict__ vTb,
                                              unsigned short* __restrict__ op,
                                              rowstat* __restrict__ st) {
    __shared__ __attribute__((aligned(16))) char klds[32 * 512];            // 16KB swizzled K
    __shared__ __attribute__((aligned(16))) char vlds[256 * 64];            // 16KB swizzled V^T
    __shared__ __attribute__((aligned(16))) unsigned int p_lds[4][16 * 16]; // 4KB bf16 P
    const int tid = threadIdx.x;
    const int w = tid >> 6, lane = tid & 63;
    const int c = lane & 15, g = lane >> 4;
    const int bid = blockIdx.x;                    // 1024
    const int swz = (bid & 7) * 128 + (bid >> 3);  // bijective XCD swizzle (1024%8==0)
    const int part = swz & 1;                      // both parts of a (b,qt) on same XCD
    const int rest = swz >> 1;
    const int b = rest >> 5;
    const int qt = rest & 31;
    const int qbase = qt * 64 + w * 16;
    const int kt0 = part * 32;
    constexpr int NT = 32;  // key-tiles per part (32 keys each)

    op += (size_t)part * BB * NN * DD;  // route to Op0 / Op1
    st += (size_t)part * BB * NN;       // route to st0 / st1

    const int sl_sub = lane >> 5;
    const int sl_col = (lane & 31) * 16;
    const int vrow = lane >> 2;
    const int vcol = (((lane & 3) ^ (vrow & 3)) << 4);  // pre-swizzled V source

    const short8* qp = (const short8*)(qb + (size_t)(b * NN + qbase + c) * DD + g * 8);
    short8 qf[8];
#pragma unroll
    for (int kc = 0; kc < 8; kc++) qf[kc] = qp[kc * 4];

    const char* kb_bytes = (const char*)(kb + (size_t)(b * NN) * DD);
    const char* vb_bytes = (const char*)(vTb + (size_t)(b * DD) * NN);
    const int kswz = (c & 7) << 4;
    const int pswz = (c & 3) << 2;
    const int vswz = (c & 3) << 4;

#define STAGE_KV(kt_) do {                                                               \
        const char* gk = kb_bytes + ((size_t)((kt_) * 32 + 8 * w)) * 512;                \
        _Pragma("unroll")                                                                \
        for (int s_ = 0; s_ < 4; s_++) {                                                 \
            int row_lo = 2 * s_ + sl_sub;                                                \
            gload_lds16(gk + (size_t)row_lo * 512 + (sl_col ^ (row_lo << 4)),            \
                        &klds[0] + (w * 4 + s_) * 1024);                                 \
        }                                                                                \
        const char* gv = vb_bytes + ((size_t)(64 * w + vrow) * NN + (kt_) * 32) * 2 + vcol; \
        _Pragma("unroll")                                                                \
        for (int s_ = 0; s_ < 4; s_++) {                                                 \
            gload_lds16(gv + (size_t)(16 * s_) * NN * 2,                                 \
                        &vlds[0] + (w * 4 + s_) * 1024);                                 \
        }                                                                                \
    } while (0)

    f32x4 oacc[16];
#pragma unroll
    for (int i = 0; i < 16; i++) oacc[i] = (f32x4){0.f, 0.f, 0.f, 0.f};
    float mrun = -INFINITY;
    float lrun = 0.f;
    unsigned int* pl = &p_lds[w][0];

    for (int t = 0; t < NT; t++) {
        int kt = kt0 + t;
        STAGE_KV(kt);
        asm volatile("s_waitcnt vmcnt(0)" ::: "memory");
        __builtin_amdgcn_s_barrier();  // B1: tile staged & published
        fence_mem();

        // ---- swapped QK^T: lane holds keys {4g+r, 16+4g+r}, q=c ----
        f32x4 s0 = (f32x4){0.f, 0.f, 0.f, 0.f};
        f32x4 s1 = (f32x4){0.f, 0.f, 0.f, 0.f};
        __builtin_amdgcn_s_setprio(1);
#pragma unroll
        for (int kc = 0; kc < 8; kc++) {
            short8 qv = qf[kc];
            int col = (kc * 64 + g * 16) ^ kswz;
            short8 kf0 = *(const short8*)(&klds[0] + (size_t)c * 512 + col);
            short8 kf1 = *(const short8*)(&klds[0] + (size_t)(c + 16) * 512 + col);
            s0 = MFMA16(kf0, qv, s0);
            s1 = MFMA16(kf1, qv, s1);
        }
        __builtin_amdgcn_s_setprio(0);

        // ---- in-lane softmax (8 keys per lane) ----
        float t0 = fmaxf(fmaxf(s0[0], s0[1]), fmaxf(s0[2], s0[3]));
        float t1 = fmaxf(fmaxf(s1[0], s1[1]), fmaxf(s1[2], s1[3]));
        float tmax = fmaxf(t0, t1);
        tmax = fmaxf(tmax, __shfl_xor(tmax, 16));
        tmax = fmaxf(tmax, __shfl_xor(tmax, 32));

        bool need = tmax > mrun + 8.f;
        if (__any(need)) {
            float mn = fmaxf(mrun, tmax);
            float corr = __expf(mrun - mn);
#pragma unroll
            for (int r = 0; r < 4; r++) s0[r] = __expf(s0[r] - mn);
#pragma unroll
            for (int r = 0; r < 4; r++) s1[r] = __expf(s1[r] - mn);
            lrun = lrun * corr + ((s0[0] + s0[1]) + (s0[2] + s0[3])) +
                   ((s1[0] + s1[1]) + (s1[2] + s1[3]));
            mrun = mn;
#pragma unroll
            for (int r = 0; r < 4; r++) {
                float cr = __shfl(corr, 20 * g + r);
#pragma unroll
                for (int nc = 0; nc < 16; nc++) oacc[nc][r] *= cr;
            }
        } else {
#pragma unroll
            for (int r = 0; r < 4; r++) s0[r] = __expf(s0[r] - mrun);
#pragma unroll
            for (int r = 0; r < 4; r++) s1[r] = __expf(s1[r] - mrun);
            lrun += ((s0[0] + s0[1]) + (s0[2] + s0[3])) +
                    ((s1[0] + s1[1]) + (s1[2] + s1[3]));
        }

        // ---- pack P to bf16, swizzled per-wave LDS [q=c][16 dwords] ----
        {
            unsigned int pw;
            pw = (unsigned int)f2bf(s0[0]) | ((unsigned int)f2bf(s0[1]) << 16);
            pl[c * 16 + ((2 * g + 0) ^ pswz)] = pw;
            pw = (unsigned int)f2bf(s0[2]) | ((unsigned int)f2bf(s0[3]) << 16);
            pl[c * 16 + ((2 * g + 1) ^ pswz)] = pw;
            pw = (unsigned int)f2bf(s1[0]) | ((unsigned int)f2bf(s1[1]) << 16);
            pl[c * 16 + ((8 + 2 * g + 0) ^ pswz)] = pw;
            pw = (unsigned int)f2bf(s1[2]) | ((unsigned int)f2bf(s1[3]) << 16);
            pl[c * 16 + ((8 + 2 * g + 1) ^ pswz)] = pw;
        }
        short8 pf = *(const short8*)(pl + c * 16 + ((4 * g) ^ pswz));

        // ---- PV from swizzled LDS ----
        __builtin_amdgcn_s_setprio(1);
#pragma unroll
        for (int nc = 0; nc < 16; nc++) {
            short8 vf = *(const short8*)(&vlds[0] + (size_t)(16 * nc + c) * 64 + ((g * 16) ^ vswz));
            oacc[nc] = MFMA16(pf, vf, oacc[nc]);
        }
        __builtin_amdgcn_s_setprio(0);

        fence_mem();
        __builtin_amdgcn_s_barrier();  // B2: all waves done with this tile
        fence_mem();
    }
#undef STAGE_KV

    // ---- epilogue: normalized partial O + (m,l) stats ----
    float lt = lrun;
    lt += __shfl_xor(lt, 16);
    lt += __shfl_xor(lt, 32);
    float inv_r[4];
#pragma unroll
    for (int r = 0; r < 4; r++) inv_r[r] = 1.f / __shfl(lt, 20 * g + r);
#pragma unroll
    for (int r = 0; r < 4; r++) {
        size_t rowoff = (size_t)(b * NN + qbase + 4 * g + r) * DD;
#pragma unroll
        for (int nc = 0; nc < 16; nc++) {
            op[rowoff + nc * 16 + c] = f2bf(oacc[nc][r] * inv_r[r]);
        }
    }
    if (g == 0) {
        rowstat s; s.m = mrun; s.l = lt;
        st[b * NN + qbase + c] = s;
    }
}

// ---- merge split-K partials ----
__global__ __launch_bounds__(256) void merge_k(const unsigned short* __restrict__ O0,
                                               const unsigned short* __restrict__ O1,
                                               const rowstat* __restrict__ st0,
                                               const rowstat* __restrict__ st1,
                                               unsigned short* __restrict__ o) {
    int t = threadIdx.x;
    int row = blockIdx.x * 64 + (t >> 2);
    rowstat s0 = st0[row], s1 = st1[row];
    float M = fmaxf(s0.m, s1.m);
    float w0 = __expf(s0.m - M) * s0.l;
    float w1 = __expf(s1.m - M) * s1.l;
    float inv = 1.f / (w0 + w1);
    w0 *= inv; w1 *= inv;
    const short8* p0 = (const short8*)(O0 + (size_t)row * 256 + (t & 3) * 64);
    const short8* p1 = (const short8*)(O1 + (size_t)row * 256 + (t & 3) * 64);
    short8* po = (short8*)(o + (size_t)row * 256 + (t & 3) * 64);
#pragma unroll
    for (int j = 0; j < 8; j++) {
        short8 a = p0[j], b = p1[j], r;
#pragma unroll
        for (int e = 0; e < 8; e++)
            r[e] = (short)f2bf(w0 * bf2f((unsigned short)a[e]) + w1 * bf2f((unsigned short)b[e]));
        po[j] = r;
    }
}

// ---- fused FFN2a + gelu + mean ----
__global__ __launch_bounds__(256) void out_mean_k(const unsigned short* __restrict__ A,
                                                  const unsigned short* __restrict__ W2aT,
                                                  const float* __restrict__ b2a,
                                                  float* __restrict__ bar) {
    const int w = threadIdx.x >> 6, lane = threadIdx.x & 63;
    const int c = lane & 15, g = lane >> 4;
    const int rb = blockIdx.x * 64 + w * 16;
    const int bb = (blockIdx.x * 64) >> 11;

    const short8* ap = (const short8*)(A + (size_t)(rb + c) * 256 + g * 8);
    f32x4 acc[16];
#pragma unroll
    for (int n = 0; n < 16; n++) acc[n] = (f32x4){0.f, 0.f, 0.f, 0.f};
#pragma unroll
    for (int kc = 0; kc < 8; kc++) {
        short8 a = ap[kc * 4];
#pragma unroll
        for (int n = 0; n < 16; n++) {
            short8 bfr = *(const short8*)(W2aT + (size_t)(n * 16 + c) * 256 + kc * 32 + g * 8);
            acc[n] = MFMA16(a, bfr, acc[n]);
        }
    }
#pragma unroll
    for (int n = 0; n < 16; n++) {
        int col = n * 16 + c;
        float bv = b2a[col];
        float s = 0.f;
#pragma unroll
        for (int r = 0; r < 4; r++) s += gelu_exact(acc[n][r] + bv);
        s += __shfl_xor(s, 16);
        s += __shfl_xor(s, 32);
        if (g == 0) atomicAdd(&bar[bb * 256 + col], s);
    }
}

// ---- final projection ----
__global__ void final_k(const float* __restrict__ bar, const float* __restrict__ W2b,
                        const float* __restrict__ b2b, float* __restrict__ out) {
    int b = blockIdx.x, d = threadIdx.x;
    float s = 0.f;
    for (int h = 0; h < HH; h++) s += bar[b * HH + h] * W2b[h * DD + d];
    out[b * DD + d] = b2b[d] + s * (1.f / (float)NN);
}

extern "C" void kernel_launch(void* const* d_in, const int* in_sizes, int n_in,
                              void* d_out, int out_size, void* d_ws, size_t ws_size,
                              hipStream_t stream) {
    (void)in_sizes; (void)n_in; (void)out_size; (void)ws_size;
    const float* x    = (const float*)d_in[0];
    const float* grd  = (const float*)d_in[1];
    const float* W1a  = (const float*)d_in[2];
    const float* b1a  = (const float*)d_in[3];
    const float* W1b  = (const float*)d_in[4];
    const float* b1b  = (const float*)d_in[5];
    const float* Wqkv = (const float*)d_in[6];
    const float* W2a  = (const float*)d_in[7];
    const float* b2a  = (const float*)d_in[8];
    const float* W2b  = (const float*)d_in[9];
    const float* b2b  = (const float*)d_in[10];
    float* out = (float*)d_out;

    char* ws = (char*)d_ws;
    const size_t MB = 1024 * 1024;
    unsigned short* q_buf  = (unsigned short*)(ws + 0);        // 16MB; merged o reuses
    unsigned short* k_buf  = (unsigned short*)(ws + 16 * MB);
    unsigned short* vT_buf = (unsigned short*)(ws + 32 * MB);
    unsigned short* Op0    = (unsigned short*)(ws + 48 * MB);
    rowstat*        st0    = (rowstat*)(ws + 80 * MB);
    unsigned short* W1bT   = (unsigned short*)(ws + 80 * MB + 512 * 1024);
    unsigned short* WqkvT  = (unsigned short*)(ws + 80 * MB + 640 * 1024);
    unsigned short* W2aT   = (unsigned short*)(ws + 81 * MB);
    float*          bar    = (float*)(ws + 81 * MB + 256 * 1024);
    unsigned short* Op1    = Op0 + (size_t)BB * NN * DD;
    rowstat*        st1    = st0 + BB * NN;

    transposeT_k<<<dim3(80), 256, 0, stream>>>(W1b, Wqkv, W2a, W1bT, WqkvT, W2aT);
    ffn_qkv_k<<<dim3(512), 256, 0, stream>>>(x, grd, W1a, b1a, W1bT, b1b, WqkvT,
                                             q_buf, k_buf, vT_buf);
    attn_k<<<dim3(1024), 256, 0, stream>>>(q_buf, k_buf, vT_buf, Op0, st0);
    merge_k<<<dim3(512), 256, 0, stream>>>(Op0, Op1, st0, st1, q_buf);
    hipMemsetAsync(bar, 0, BB * HH * sizeof(float), stream);
    out_mean_k<<<dim3(512), 256, 0, stream>>>(q_buf, W2aT, b2a, bar);
    final_k<<<dim3(BB), 256, 0, stream>>>(bar, W2b, b2b, out);
}

// Round 10
// 355.423 us; speedup vs baseline: 1.2027x; 1.2027x over previous
//
#include <hip/hip_runtime.h>
#include <hip/hip_bf16.h>
#include <cmath>

typedef __attribute__((ext_vector_type(8))) short short8;
typedef __attribute__((ext_vector_type(4))) float f32x4;

#define MFMA16(a, b, c) __builtin_amdgcn_mfma_f32_16x16x32_bf16((a), (b), (c), 0, 0, 0)

static constexpr int BB = 16, NN = 2048, DD = 256, HH = 256;

__device__ inline unsigned short f2bf(float f) {
    union { float f; unsigned int u; } v; v.f = f;
    unsigned int r = v.u + 0x7fffu + ((v.u >> 16) & 1u);
    return (unsigned short)(r >> 16);
}
__device__ inline float bf2f(unsigned short u) {
    union { unsigned int u; float f; } v; v.u = ((unsigned int)u) << 16;
    return v.f;
}
__device__ inline float gelu_exact(float x) {
    return 0.5f * x * (1.0f + erff(x * 0.7071067811865475f));
}
__device__ inline void gload_lds16(const void* g, void* l) {
    __builtin_amdgcn_global_load_lds(
        (const __attribute__((address_space(1))) unsigned int*)g,
        (__attribute__((address_space(3))) unsigned int*)l, 16, 0, 0);
}
__device__ inline void fence_mem() { asm volatile("" ::: "memory"); }

// ---- tiled weight transpose: fp32 [256][N] -> bf16 [N][256], coalesced ----
__global__ __launch_bounds__(256) void transposeT_k(const float* __restrict__ W1b,
                                                    const float* __restrict__ Wqkv,
                                                    const float* __restrict__ W2a,
                                                    unsigned short* __restrict__ W1bT,
                                                    unsigned short* __restrict__ WqkvT,
                                                    unsigned short* __restrict__ W2aT) {
    __shared__ float tl[64][65];
    int bid = blockIdx.x;  // 80 blocks: 16 W1b, 48 Wqkv, 16 W2a
    const float* src;
    unsigned short* dst;
    int N, tn, tk;
    if (bid < 16) {
        src = W1b; dst = W1bT; N = 256; tn = bid & 3; tk = bid >> 2;
    } else if (bid < 64) {
        int t2 = bid - 16;
        src = Wqkv; dst = WqkvT; N = 768; tn = t2 % 12; tk = t2 / 12;
    } else {
        int t2 = bid - 64;
        src = W2a; dst = W2aT; N = 256; tn = t2 & 3; tk = t2 >> 2;
    }
    int n0 = tn * 64, k0 = tk * 64;
    int t = threadIdx.x;
#pragma unroll
    for (int j = 0; j < 4; j++) {
        int row = (t >> 4) * 4 + j;
        f32x4 v = *(const f32x4*)(src + (size_t)(k0 + row) * N + n0 + (t & 15) * 4);
#pragma unroll
        for (int e = 0; e < 4; e++) tl[row][(t & 15) * 4 + e] = v[e];
    }
    __syncthreads();
    int n = t >> 2, cb = (t & 3) * 16;
    short8 a, b;
#pragma unroll
    for (int e = 0; e < 8; e++) {
        a[e] = (short)f2bf(tl[cb + e][n]);
        b[e] = (short)f2bf(tl[cb + 8 + e][n]);
    }
    *(short8*)(dst + (size_t)(n0 + n) * 256 + k0 + cb) = a;
    *(short8*)(dst + (size_t)(n0 + n) * 256 + k0 + cb + 8) = b;
}

// ---- fused FFN1 + qkv: t inline -> h (per-wave LDS) -> q,k,v ----
__global__ __launch_bounds__(256) void ffn_qkv_k(const float* __restrict__ x,
                                                 const float* __restrict__ grd,
                                                 const float* __restrict__ W1a,
                                                 const float* __restrict__ b1a,
                                                 const unsigned short* __restrict__ W1bT,
                                                 const float* __restrict__ b1b,
                                                 const unsigned short* __restrict__ WqkvT,
                                                 unsigned short* __restrict__ qo,
                                                 unsigned short* __restrict__ ko,
                                                 unsigned short* __restrict__ vo) {
    __shared__ unsigned short h_lds[4][16 * 256];
    const int w = threadIdx.x >> 6, lane = threadIdx.x & 63;
    const int c = lane & 15, g = lane >> 4;
    const int rb = blockIdx.x * 64 + w * 16;
    const int bb = (blockIdx.x * 64) >> 11;
    const int rowinb = (rb & (NN - 1)) + c;

    const int p = rb + c;
    const float xv = x[p];
    const float gv = grd[p & (NN - 1)];
    short8 tf[8];
#pragma unroll
    for (int kc = 0; kc < 8; kc++) {
        int j0 = kc * 32 + g * 8;
#pragma unroll
        for (int e = 0; e < 8; e += 4) {
            f32x4 wa = *(const f32x4*)(W1a + j0 + e);
            f32x4 wb = *(const f32x4*)(W1a + 256 + j0 + e);
            f32x4 ba = *(const f32x4*)(b1a + j0 + e);
#pragma unroll
            for (int q = 0; q < 4; q++) {
                float v = xv * wa[q] + gv * wb[q] + ba[q];
                tf[kc][e + q] = (short)f2bf(gelu_exact(v));
            }
        }
    }

    f32x4 acc[16];
#pragma unroll
    for (int n = 0; n < 16; n++) acc[n] = (f32x4){0.f, 0.f, 0.f, 0.f};
#pragma unroll
    for (int kc = 0; kc < 8; kc++) {
        short8 a = tf[kc];
#pragma unroll
        for (int n = 0; n < 16; n++) {
            short8 bfr = *(const short8*)(W1bT + (size_t)(n * 16 + c) * 256 + kc * 32 + g * 8);
            acc[n] = MFMA16(a, bfr, acc[n]);
        }
    }
    unsigned short* hl = &h_lds[w][0];
#pragma unroll
    for (int n = 0; n < 16; n++) {
        int col = n * 16 + c;
        float bv = b1b[col];
#pragma unroll
        for (int r = 0; r < 4; r++) {
            int row = g * 4 + r;
            hl[row * 256 + (col ^ ((row & 7) << 3))] = f2bf(acc[n][r] + bv);
        }
    }
    short8 hf[8];
#pragma unroll
    for (int kc = 0; kc < 8; kc++) {
        hf[kc] = *(const short8*)(hl + c * 256 + ((kc * 32 + g * 8) ^ ((c & 7) << 3)));
    }

    // q (scaled 1/16)
#pragma unroll
    for (int n = 0; n < 16; n++) acc[n] = (f32x4){0.f, 0.f, 0.f, 0.f};
#pragma unroll
    for (int kc = 0; kc < 8; kc++) {
        short8 a = hf[kc];
#pragma unroll
        for (int n = 0; n < 16; n++) {
            short8 bfr = *(const short8*)(WqkvT + (size_t)(n * 16 + c) * 256 + kc * 32 + g * 8);
            acc[n] = MFMA16(a, bfr, acc[n]);
        }
    }
#pragma unroll
    for (int n = 0; n < 16; n++)
#pragma unroll
        for (int r = 0; r < 4; r++)
            qo[(size_t)(rb + g * 4 + r) * 256 + n * 16 + c] = f2bf(acc[n][r] * 0.0625f);

    // k
#pragma unroll
    for (int n = 0; n < 16; n++) acc[n] = (f32x4){0.f, 0.f, 0.f, 0.f};
#pragma unroll
    for (int kc = 0; kc < 8; kc++) {
        short8 a = hf[kc];
#pragma unroll
        for (int n = 0; n < 16; n++) {
            short8 bfr = *(const short8*)(WqkvT + (size_t)(256 + n * 16 + c) * 256 + kc * 32 + g * 8);
            acc[n] = MFMA16(a, bfr, acc[n]);
        }
    }
#pragma unroll
    for (int n = 0; n < 16; n++)
#pragma unroll
        for (int r = 0; r < 4; r++)
            ko[(size_t)(rb + g * 4 + r) * 256 + n * 16 + c] = f2bf(acc[n][r]);

    // v (swapped operands -> v^T)
#pragma unroll
    for (int m = 0; m < 16; m++) acc[m] = (f32x4){0.f, 0.f, 0.f, 0.f};
#pragma unroll
    for (int kc = 0; kc < 8; kc++) {
        short8 b = hf[kc];
#pragma unroll
        for (int m = 0; m < 16; m++) {
            short8 afr = *(const short8*)(WqkvT + (size_t)(512 + m * 16 + c) * 256 + kc * 32 + g * 8);
            acc[m] = MFMA16(afr, b, acc[m]);
        }
    }
#pragma unroll
    for (int m = 0; m < 16; m++) {
#pragma unroll
        for (int r = 0; r < 4; r++) {
            int dcol = m * 16 + g * 4 + r;
            vo[((size_t)(bb * 256 + dcol)) * NN + rowinb] = f2bf(acc[m][r]);
        }
    }
}

// ---- flash attention: 8-wave blocks, KVBLK=64, split-D wave pairs, oacc[8] ----
// wave w: qsub=w&3 (16 q-rows), dhalf=w>>2 (128 d-cols); computes S for keys
// [dhalf*32,+32), exchanges row-max with partner w^4, PV over all 64 keys on its d-half.
__global__ __launch_bounds__(512) void attn_k(const unsigned short* __restrict__ qb,
                                              const unsigned short* __restrict__ kb,
                                              const unsigned short* __restrict__ vTb,
                                              unsigned short* __restrict__ ob) {
    __shared__ __attribute__((aligned(16))) char klds[64 * 512];             // 32KB swizzled K
    __shared__ __attribute__((aligned(16))) char vlds[256 * 128];            // 32KB swizzled V^T
    __shared__ __attribute__((aligned(16))) unsigned int p_lds[4][16 * 32];  // 8KB bf16 P (per qsub)
    __shared__ float ex_m[8][16];                                            // max exchange
    __shared__ float ex_l[8][16];                                            // sum exchange
    const int tid = threadIdx.x;
    const int w = tid >> 6, lane = tid & 63;
    const int c = lane & 15, g = lane >> 4;
    const int qsub = w & 3, dhalf = w >> 2;
    const int khalf = dhalf;
    const int bid = blockIdx.x;
    const int swz = (bid & 7) * 64 + (bid >> 3);  // bijective XCD swizzle (512%8==0)
    const int b = swz >> 5;
    const int qt = swz & 31;
    const int qbase = qt * 64 + qsub * 16;
    constexpr int NT = NN / 64;  // 32 key-tiles

    // staging lane geometry
    const int sl_sub = lane >> 5;          // K: row parity within pair
    const int sl_col = (lane & 31) * 16;   // K: byte col
    const int vl_row = lane >> 3;          // V: d-row 0..7 within instr
    const size_t vl_off = (size_t)vl_row * (NN * 2) + (size_t)(((lane & 7) ^ vl_row) << 4);

    const short8* qp = (const short8*)(qb + (size_t)(b * NN + qbase + c) * DD + g * 8);
    short8 qf[8];
#pragma unroll
    for (int kc = 0; kc < 8; kc++) qf[kc] = qp[kc * 4];

    const char* kb_bytes = (const char*)(kb + (size_t)(b * NN) * DD);
    const char* vb_bytes = (const char*)(vTb + (size_t)(b * DD) * NN);
    const int kswz = (c & 7) << 4;   // K read-side XOR (bytes)
    const int pcs = c & 7;           // P/V chunk swizzle (4-dword / 16B granular)

    // per iter per wave: 4 K-instrs (rows 8w..8w+7) + 4 V-instrs (d-rows 32w..32w+31)
#define STAGE_KV(kt_) do {                                                               \
        const char* gk = kb_bytes + ((size_t)((kt_) * 64 + 8 * w)) * 512;                \
        _Pragma("unroll")                                                                \
        for (int s_ = 0; s_ < 4; s_++) {                                                 \
            int row_lo = 2 * s_ + sl_sub;                                                \
            gload_lds16(gk + (size_t)row_lo * 512 + (sl_col ^ (row_lo << 4)),            \
                        &klds[0] + (8 * w + 2 * s_) * 512);                              \
        }                                                                                \
        const char* gv = vb_bytes + (size_t)(32 * w) * (NN * 2) + (size_t)(kt_) * 128 + vl_off; \
        _Pragma("unroll")                                                                \
        for (int s_ = 0; s_ < 4; s_++) {                                                 \
            gload_lds16(gv + (size_t)(8 * s_) * (NN * 2),                                \
                        &vlds[0] + (32 * w + 8 * s_) * 128);                             \
        }                                                                                \
    } while (0)

    f32x4 oacc[8];
#pragma unroll
    for (int i = 0; i < 8; i++) oacc[i] = (f32x4){0.f, 0.f, 0.f, 0.f};
    float mrun = -INFINITY;  // running max for q-row c (identical across pair)
    float lrun = 0.f;        // per-lane partial sum (this lane's 8 keys of own half)
    unsigned int* plw = &p_lds[qsub][c * 32];

    for (int kt = 0; kt < NT; kt++) {
        STAGE_KV(kt);
        asm volatile("s_waitcnt vmcnt(0)" ::: "memory");
        __builtin_amdgcn_s_barrier();  // B1: K+V tile staged
        fence_mem();

        // ---- swapped QK^T for own 32-key half: lane holds keys khalf*32+{4g+r,16+4g+r}, q=c
        const char* klb = &klds[0] + (size_t)(khalf * 32) * 512;
        f32x4 s0 = (f32x4){0.f, 0.f, 0.f, 0.f};
        f32x4 s1 = (f32x4){0.f, 0.f, 0.f, 0.f};
        __builtin_amdgcn_s_setprio(1);
#pragma unroll
        for (int kc = 0; kc < 8; kc++) {
            short8 qv = qf[kc];
            int col = (kc * 64 + g * 16) ^ kswz;
            short8 kf0 = *(const short8*)(klb + (size_t)c * 512 + col);
            short8 kf1 = *(const short8*)(klb + (size_t)(c + 16) * 512 + col);
            s0 = MFMA16(kf0, qv, s0);
            s1 = MFMA16(kf1, qv, s1);
        }
        __builtin_amdgcn_s_setprio(0);

        // ---- own-half row max (all lanes hold it for q=c after shfl) ----
        float t0 = fmaxf(fmaxf(s0[0], s0[1]), fmaxf(s0[2], s0[3]));
        float t1 = fmaxf(fmaxf(s1[0], s1[1]), fmaxf(s1[2], s1[3]));
        float tmo = fmaxf(t0, t1);
        tmo = fmaxf(tmo, __shfl_xor(tmo, 16));
        tmo = fmaxf(tmo, __shfl_xor(tmo, 32));
        if (g == 0) ex_m[w][c] = tmo;
        fence_mem();
        __builtin_amdgcn_s_barrier();  // B2: partner max visible
        fence_mem();
        float tmax = fmaxf(tmo, ex_m[w ^ 4][c]);  // combined 64-key row max

        bool need = tmax > mrun + 8.f;
        if (__any(need)) {
            float mn = fmaxf(mrun, tmax);
            float corr = __expf(mrun - mn);
#pragma unroll
            for (int r = 0; r < 4; r++) s0[r] = __expf(s0[r] - mn);
#pragma unroll
            for (int r = 0; r < 4; r++) s1[r] = __expf(s1[r] - mn);
            lrun = lrun * corr + ((s0[0] + s0[1]) + (s0[2] + s0[3])) +
                   ((s1[0] + s1[1]) + (s1[2] + s1[3]));
            mrun = mn;
#pragma unroll
            for (int r = 0; r < 4; r++) {
                float cr = __shfl(corr, 20 * g + r);  // lane with c'=4g+r
#pragma unroll
                for (int nc = 0; nc < 8; nc++) oacc[nc][r] *= cr;
            }
        } else {
#pragma unroll
            for (int r = 0; r < 4; r++) s0[r] = __expf(s0[r] - mrun);
#pragma unroll
            for (int r = 0; r < 4; r++) s1[r] = __expf(s1[r] - mrun);
            lrun += ((s0[0] + s0[1]) + (s0[2] + s0[3])) +
                    ((s1[0] + s1[1]) + (s1[2] + s1[3]));
        }

        // ---- pack own P half (32 keys) into shared per-qsub buffer, chunk-swizzled ----
        {
            int jb0 = khalf * 16 + 2 * g;      // s0 dwords jb0, jb0+1
            int jb1 = khalf * 16 + 8 + 2 * g;  // s1
            unsigned int pw;
#pragma unroll
            for (int h = 0; h < 2; h++) {
                int j = jb0 + h;
                pw = (unsigned int)f2bf(s0[2 * h]) | ((unsigned int)f2bf(s0[2 * h + 1]) << 16);
                plw[(((j >> 2) ^ pcs) << 2) | (j & 3)] = pw;
                j = jb1 + h;
                pw = (unsigned int)f2bf(s1[2 * h]) | ((unsigned int)f2bf(s1[2 * h + 1]) << 16);
                plw[(((j >> 2) ^ pcs) << 2) | (j & 3)] = pw;
            }
        }
        fence_mem();
        __builtin_amdgcn_s_barrier();  // B3: both P halves of every qsub written
        fence_mem();

        // ---- PV: O[16q x 128d-half] += P(16x64) @ V(64x128half), both from LDS ----
        short8 pf0 = *(const short8*)(plw + ((g ^ pcs) << 2));
        short8 pf1 = *(const short8*)(plw + (((4 + g) ^ pcs) << 2));
        __builtin_amdgcn_s_setprio(1);
#pragma unroll
        for (int nc = 0; nc < 8; nc++) {
            const char* vr = &vlds[0] + (size_t)(dhalf * 128 + nc * 16 + c) * 128;
            short8 vf0 = *(const short8*)(vr + ((g ^ pcs) << 4));
            short8 vf1 = *(const short8*)(vr + (((4 + g) ^ pcs) << 4));
            oacc[nc] = MFMA16(pf0, vf0, oacc[nc]);
            oacc[nc] = MFMA16(pf1, vf1, oacc[nc]);
        }
        __builtin_amdgcn_s_setprio(0);

        fence_mem();
        __builtin_amdgcn_s_barrier();  // B4: all waves done reading K/V/P for this tile
        fence_mem();
    }
#undef STAGE_KV

    // ---- epilogue: combine l across pair, normalize, store own d-half ----
    float lt = lrun;
    lt += __shfl_xor(lt, 16);
    lt += __shfl_xor(lt, 32);  // own-half sum for q=c
    if (g == 0) ex_l[w][c] = lt;
    fence_mem();
    __builtin_amdgcn_s_barrier();
    fence_mem();
    lt += ex_l[w ^ 4][c];  // full 2048-key sum
    float inv_r[4];
#pragma unroll
    for (int r = 0; r < 4; r++) inv_r[r] = 1.f / __shfl(lt, 20 * g + r);
#pragma unroll
    for (int r = 0; r < 4; r++) {
        size_t rowoff = (size_t)(b * NN + qbase + 4 * g + r) * DD + dhalf * 128;
#pragma unroll
        for (int nc = 0; nc < 8; nc++) {
            ob[rowoff + nc * 16 + c] = f2bf(oacc[nc][r] * inv_r[r]);
        }
    }
}

// ---- fused FFN2a + gelu + mean ----
__global__ __launch_bounds__(256) void out_mean_k(const unsigned short* __restrict__ A,
                                                  const unsigned short* __restrict__ W2aT,
                                                  const float* __restrict__ b2a,
                                                  float* __restrict__ bar) {
    const int w = threadIdx.x >> 6, lane = threadIdx.x & 63;
    const int c = lane & 15, g = lane >> 4;
    const int rb = blockIdx.x * 64 + w * 16;
    const int bb = (blockIdx.x * 64) >> 11;

    const short8* ap = (const short8*)(A + (size_t)(rb + c) * 256 + g * 8);
    f32x4 acc[16];
#pragma unroll
    for (int n = 0; n < 16; n++) acc[n] = (f32x4){0.f, 0.f, 0.f, 0.f};
#pragma unroll
    for (int kc = 0; kc < 8; kc++) {
        short8 a = ap[kc * 4];
#pragma unroll
        for (int n = 0; n < 16; n++) {
            short8 bfr = *(const short8*)(W2aT + (size_t)(n * 16 + c) * 256 + kc * 32 + g * 8);
            acc[n] = MFMA16(a, bfr, acc[n]);
        }
    }
#pragma unroll
    for (int n = 0; n < 16; n++) {
        int col = n * 16 + c;
        float bv = b2a[col];
        float s = 0.f;
#pragma unroll
        for (int r = 0; r < 4; r++) s += gelu_exact(acc[n][r] + bv);
        s += __shfl_xor(s, 16);
        s += __shfl_xor(s, 32);
        if (g == 0) atomicAdd(&bar[bb * 256 + col], s);
    }
}

// ---- final projection ----
__global__ void final_k(const float* __restrict__ bar, const float* __restrict__ W2b,
                        const float* __restrict__ b2b, float* __restrict__ out) {
    int b = blockIdx.x, d = threadIdx.x;
    float s = 0.f;
    for (int h = 0; h < HH; h++) s += bar[b * HH + h] * W2b[h * DD + d];
    out[b * DD + d] = b2b[d] + s * (1.f / (float)NN);
}

extern "C" void kernel_launch(void* const* d_in, const int* in_sizes, int n_in,
                              void* d_out, int out_size, void* d_ws, size_t ws_size,
                              hipStream_t stream) {
    (void)in_sizes; (void)n_in; (void)out_size; (void)ws_size;
    const float* x    = (const float*)d_in[0];
    const float* grd  = (const float*)d_in[1];
    const float* W1a  = (const float*)d_in[2];
    const float* b1a  = (const float*)d_in[3];
    const float* W1b  = (const float*)d_in[4];
    const float* b1b  = (const float*)d_in[5];
    const float* Wqkv = (const float*)d_in[6];
    const float* W2a  = (const float*)d_in[7];
    const float* b2a  = (const float*)d_in[8];
    const float* W2b  = (const float*)d_in[9];
    const float* b2b  = (const float*)d_in[10];
    float* out = (float*)d_out;

    char* ws = (char*)d_ws;
    const size_t MB = 1024 * 1024;
    unsigned short* q_buf  = (unsigned short*)(ws + 0);
    unsigned short* k_buf  = (unsigned short*)(ws + 16 * MB);
    unsigned short* vT_buf = (unsigned short*)(ws + 32 * MB);
    unsigned short* o_buf  = (unsigned short*)(ws + 48 * MB);
    unsigned short* W1bT   = (unsigned short*)(ws + 80 * MB);
    unsigned short* WqkvT  = (unsigned short*)(ws + 80 * MB + 512 * 1024);
    unsigned short* W2aT   = (unsigned short*)(ws + 81 * MB);
    float*          bar    = (float*)(ws + 81 * MB + 256 * 1024);

    transposeT_k<<<dim3(80), 256, 0, stream>>>(W1b, Wqkv, W2a, W1bT, WqkvT, W2aT);
    ffn_qkv_k<<<dim3(512), 256, 0, stream>>>(x, grd, W1a, b1a, W1bT, b1b, WqkvT,
                                             q_buf, k_buf, vT_buf);
    attn_k<<<dim3(512), 512, 0, stream>>>(q_buf, k_buf, vT_buf, o_buf);
    hipMemsetAsync(bar, 0, BB * HH * sizeof(float), stream);
    out_mean_k<<<dim3(512), 256, 0, stream>>>(o_buf, W2aT, b2a, bar);
    final_k<<<dim3(BB), 256, 0, stream>>>(bar, W2b, b2b, out);
}